// Round 1
// baseline (307.502 us; speedup 1.0000x reference)
//
#include <hip/hip_runtime.h>
#include <hip/hip_bf16.h>

typedef short s8v  __attribute__((ext_vector_type(8)));
typedef float f16v __attribute__((ext_vector_type(16)));

__device__ __forceinline__ unsigned short f2bf(float x) {   // RTN-even
    unsigned u = __float_as_uint(x);
    unsigned r = ((u >> 16) & 1u) + 0x7FFFu;
    return (unsigned short)((u + r) >> 16);
}
__device__ __forceinline__ float bf2f(unsigned short h) {
    return __uint_as_float(((unsigned)h) << 16);
}

// ---------------- prep: relctx | bprep | hist ----------------
// X0 conversion moved to fill_kernel (overlaps there instead of delaying scans).
__global__ __launch_bounds__(256) void prep_kernel(
    const float* __restrict__ basis1, const float* __restrict__ root1,
    const float* __restrict__ basis2, const float* __restrict__ root2,
    unsigned short* __restrict__ Bp1h, unsigned short* __restrict__ Bp2h,
    const int* __restrict__ edge_index, int* __restrict__ deg, int E,
    const float* __restrict__ DAD, const float* __restrict__ rtab,
    const float* __restrict__ Wrel, float* __restrict__ Rc, int NR,
    int b1, int b2)     // b1=NR, b2=NR+640
{
    __shared__ float smem[384];
    const int b = blockIdx.x, tid = threadIdx.x;

    if (b < b1) {                        // ---- relctx ----
        float* part = smem;              // [2][128]
        float* r1s  = smem + 256;        // [128]
        int r = b;
        int o = tid & 127, q = tid >> 7;
        float s = 0.f;
        for (int j = q; j < NR; j += 2)
            s = fmaf(DAD[r * NR + j], rtab[j * 128 + o], s);
        part[q * 128 + o] = s;
        __syncthreads();
        if (tid < 128) r1s[tid] = part[tid] + part[128 + tid];
        __syncthreads();
        float s2 = 0.f;
        #pragma unroll 8
        for (int k = q * 64; k < q * 64 + 64; ++k)
            s2 = fmaf(r1s[k], Wrel[k * 128 + o], s2);
        part[q * 128 + o] = s2;
        __syncthreads();
        if (tid < 128)
            Rc[r * 128 + tid] = fmaxf(part[tid] + part[128 + tid], 0.f);
    } else if (b < b2) {                 // ---- B prep (hi only) ----
        int bb = b - b1;
        int layer = bb >= 320;
        int idx = (layer ? bb - 320 : bb) * 256 + tid;
        int n = idx & 127, k = idx >> 7;
        const float* basis = layer ? basis2 : basis1;
        const float* root  = layer ? root2  : root1;
        float v = (k < 512) ? basis[((k & 3) << 14) + ((k >> 2) << 7) + n]
                            : root[((k - 512) << 7) + n];
        size_t pos = (((size_t)(k >> 3) * 128) + n) * 8 + (k & 7);
        (layer ? Bp2h : Bp1h)[pos] = f2bf(v);
    } else {                             // ---- hist ----
        int e = (b - b2) * 256 + tid;
        if (e < E) atomicAdd(&deg[edge_index[E + e]], 1);
    }
}

// ---------------- CSR scan ----------------
__global__ __launch_bounds__(1024) void scanA_kernel(
    const int* __restrict__ deg, int* __restrict__ row_start,
    int* __restrict__ btot, int N)
{
    __shared__ int wtot[16];
    __shared__ int woff[16];
    const int tid = threadIdx.x, lane = tid & 63, wid = tid >> 6;
    int i = blockIdx.x * 1024 + tid;
    int v = (i < N) ? deg[i] : 0;
    int x = v;
    #pragma unroll
    for (int d = 1; d < 64; d <<= 1) {
        int t = __shfl_up(x, d, 64);
        if (lane >= d) x += t;
    }
    if (lane == 63) wtot[wid] = x;
    __syncthreads();
    if (wid == 0 && lane < 16) {
        int s = wtot[lane];
        int y = s;
        #pragma unroll
        for (int d = 1; d < 16; d <<= 1) {
            int t = __shfl_up(y, d, 16);
            if (lane >= d) y += t;
        }
        woff[lane] = y - s;
        if (lane == 15) btot[blockIdx.x] = y;
    }
    __syncthreads();
    if (i < N) row_start[i] = woff[wid] + (x - v);
}

// scanC with scanB inlined: every block redundantly wave-scans the <=64
// block totals (cheap), then applies its own exclusive offset.
__global__ __launch_bounds__(1024) void scanC_kernel(
    int* __restrict__ row_start, int* __restrict__ cursor,
    const int* __restrict__ btot, int nB, int N)
{
    __shared__ int incl[64];
    const int tid = threadIdx.x;
    if (tid < 64) {
        int v = (tid < nB) ? btot[tid] : 0;
        int x = v;
        #pragma unroll
        for (int d = 1; d < 64; d <<= 1) {
            int t = __shfl_up(x, d, 64);
            if (tid >= d) x += t;
        }
        incl[tid] = x;
    }
    __syncthreads();
    int off = (blockIdx.x == 0) ? 0 : incl[blockIdx.x - 1];
    int i = blockIdx.x * 1024 + tid;
    if (i < N) {
        int r = row_start[i] + off;
        row_start[i] = r;
        cursor[i]    = r;
    }
    if (blockIdx.x == (unsigned)(nB - 1) && tid == 0)
        row_start[N] = incl[nB - 1];
}

// ---------------- fill + X0 convert fused ----------------
__global__ __launch_bounds__(256) void fill_kernel(
    const int* __restrict__ edge_index, const int* __restrict__ edge_type,
    const float* __restrict__ edge_norm, int* __restrict__ cursor,
    const float* __restrict__ att1, const float* __restrict__ att2,
    int* __restrict__ src_s, float4* __restrict__ an1, float4* __restrict__ an2, int E,
    const float* __restrict__ tab, const int* __restrict__ entity,
    unsigned short* __restrict__ X0h, unsigned short* __restrict__ X0l, int N,
    int fblocks)
{
    const int b = blockIdx.x, tid = threadIdx.x;
    if (b < fblocks) {                   // ---- fill ----
        int e = b * 256 + tid;
        if (e >= E) return;
        int dst = edge_index[E + e];
        int et  = edge_type[e];
        float n = edge_norm[e];
        int pos = atomicAdd(&cursor[dst], 1);
        src_s[pos] = edge_index[e];
        float4 a1 = *(const float4*)&att1[(size_t)et * 4];
        float4 a2 = *(const float4*)&att2[(size_t)et * 4];
        an1[pos] = make_float4(n * a1.x, n * a1.y, n * a1.z, n * a1.w);
        an2[pos] = make_float4(n * a2.x, n * a2.y, n * a2.z, n * a2.w);
    } else {                             // ---- X0 = tab[entity] hi/lo ----
        int idx = (b - fblocks) * 256 + tid;   // 8 dims / thread (2 indep float4)
        int nn = idx >> 4, part = idx & 15;
        if (nn < N) {
            int src = entity[nn];
            const float4* sp = (const float4*)&tab[(size_t)src * 128 + part * 8];
            float4 v0 = sp[0], v1 = sp[1];
            float vs[8] = {v0.x, v0.y, v0.z, v0.w, v1.x, v1.y, v1.z, v1.w};
            s8v h8, l8;
            #pragma unroll
            for (int j = 0; j < 8; ++j) {
                unsigned short h = f2bf(vs[j]);
                h8[j] = (short)h;
                l8[j] = (short)f2bf(vs[j] - bf2f(h));
            }
            *(s8v*)&X0h[(size_t)nn * 128 + part * 8] = h8;
            *(s8v*)&X0l[(size_t)nn * 128 + part * 8] = l8;
        }
    }
}

// ---------------- FUSED layer: Xout = relu([agg(X)|X] @ B + bias) ----------------
// Block = 32 nodes, 256 threads. Phase A: interleaved 4-node edge gather ->
// LDS fragment-packed (slot = n ^ (kh&31)); one barrier. X-row part of the A
// operand (kh 64..79) is NOT staged: slot XOR composes to row==lane, so each
// lane loads its own row's 16B fragments straight from global (issued before
// the barrier so the barrier wait hides the latency). LDS 48KB -> 32KB.
__global__ __launch_bounds__(256) void layer_kernel(
    const unsigned short* __restrict__ Xh,    // [N,128] bf16 hi
    const unsigned short* __restrict__ Xl,    // [N,128] bf16 lo
    const int* __restrict__ row_start,
    const int* __restrict__ src_s,
    const float4* __restrict__ an,
    const unsigned short* __restrict__ Bph,   // packed [80][128][8] bf16
    const float* __restrict__ bias,
    unsigned short* __restrict__ Xoh,
    unsigned short* __restrict__ Xol,
    int N)
{
    __shared__ unsigned short Whi[64 * 32 * 8];   // 32 KB (agg part only)

    const int tid   = threadIdx.x;
    const int node0 = blockIdx.x * 32;

    // ---- phase A1: interleaved gather for 4 nodes per 32-lane group ----
    {
        int g = tid >> 5, l = tid & 31;     // lane l covers dims 4l..4l+3
        int nb = node0 + g * 4;
        int s0a[4], s1a[4];
        #pragma unroll
        for (int i = 0; i < 4; ++i) {
            int gn = nb + i;
            bool ok = gn < N;
            s0a[i] = ok ? row_start[gn] : 0;
            s1a[i] = ok ? row_start[gn + 1] : 0;
        }
        float acc[4][4][4];                 // [node][d][b]
        #pragma unroll
        for (int i = 0; i < 4; ++i)
            #pragma unroll
            for (int d = 0; d < 4; ++d)
                #pragma unroll
                for (int c = 0; c < 4; ++c) acc[i][d][c] = 0.f;

        int need = 0;
        #pragma unroll
        for (int i = 0; i < 4; ++i) need = max(need, s1a[i] - s0a[i]);

        for (int p = 0; p < need; p += 4) {
            #pragma unroll
            for (int i = 0; i < 4; ++i) {
                int q0 = s0a[i] + p;
                if (q0 < s1a[i]) {
                    int se = s1a[i] - 1;
                    int q1 = min(q0 + 1, se);
                    int q2 = min(q0 + 2, se);
                    int q3 = min(q0 + 3, se);
                    int sA = src_s[q0], sB = src_s[q1];
                    int sC = src_s[q2], sD = src_s[q3];
                    float4 aA = an[q0], aB = an[q1];
                    float4 aC = an[q2], aD = an[q3];
                    if (q0 + 1 > se) aB = make_float4(0.f, 0.f, 0.f, 0.f);
                    if (q0 + 2 > se) aC = make_float4(0.f, 0.f, 0.f, 0.f);
                    if (q0 + 3 > se) aD = make_float4(0.f, 0.f, 0.f, 0.f);
                    ushort4 hA = *(const ushort4*)&Xh[(size_t)sA * 128 + (l << 2)];
                    ushort4 hB = *(const ushort4*)&Xh[(size_t)sB * 128 + (l << 2)];
                    ushort4 hC = *(const ushort4*)&Xh[(size_t)sC * 128 + (l << 2)];
                    ushort4 hD = *(const ushort4*)&Xh[(size_t)sD * 128 + (l << 2)];
                    float xsA[4] = {bf2f(hA.x), bf2f(hA.y), bf2f(hA.z), bf2f(hA.w)};
                    float xsB[4] = {bf2f(hB.x), bf2f(hB.y), bf2f(hB.z), bf2f(hB.w)};
                    float xsC[4] = {bf2f(hC.x), bf2f(hC.y), bf2f(hC.z), bf2f(hC.w)};
                    float xsD[4] = {bf2f(hD.x), bf2f(hD.y), bf2f(hD.z), bf2f(hD.w)};
                    #pragma unroll
                    for (int d = 0; d < 4; ++d) {
                        acc[i][d][0] = fmaf(aA.x, xsA[d], fmaf(aB.x, xsB[d], fmaf(aC.x, xsC[d], fmaf(aD.x, xsD[d], acc[i][d][0]))));
                        acc[i][d][1] = fmaf(aA.y, xsA[d], fmaf(aB.y, xsB[d], fmaf(aC.y, xsC[d], fmaf(aD.y, xsD[d], acc[i][d][1]))));
                        acc[i][d][2] = fmaf(aA.z, xsA[d], fmaf(aB.z, xsB[d], fmaf(aC.z, xsC[d], fmaf(aD.z, xsD[d], acc[i][d][2]))));
                        acc[i][d][3] = fmaf(aA.w, xsA[d], fmaf(aB.w, xsB[d], fmaf(aC.w, xsC[d], fmaf(aD.w, xsD[d], acc[i][d][3]))));
                    }
                }
            }
        }
        #pragma unroll
        for (int i = 0; i < 4; ++i) {
            int n = g * 4 + i;
            float inv = 1.0f / fmaxf((float)(s1a[i] - s0a[i]), 1.0f);
            #pragma unroll
            for (int d = 0; d < 4; ++d) {
                int kh   = 2 * l + (d >> 1);
                int slot = n ^ (kh & 31);
                ushort4 h;
                h.x = f2bf(acc[i][d][0] * inv);
                h.y = f2bf(acc[i][d][1] * inv);
                h.z = f2bf(acc[i][d][2] * inv);
                h.w = f2bf(acc[i][d][3] * inv);
                *(ushort4*)&Whi[(kh * 32 + slot) * 8 + (d & 1) * 4] = h;
            }
        }
    }

    // ---- X-part A fragments direct from global (replaces old phase A2) ----
    const int lane = tid & 63, wv = tid >> 6;
    const int m    = lane & 31;
    const int kh8  = lane >> 5;
    const s8v z8 = {0, 0, 0, 0, 0, 0, 0, 0};
    s8v xh[8], xl[8];
    {
        int gn  = node0 + m;
        bool ok = gn < N;
        size_t xbase = (size_t)(ok ? gn : 0) * 128;
        #pragma unroll
        for (int q = 0; q < 8; ++q) {
            int dk = 2 * q + kh8;            // == khg - 64
            xh[q] = *(const s8v*)&Xh[xbase + dk * 8];
            xl[q] = *(const s8v*)&Xl[xbase + dk * 8];
        }
        if (!ok) {
            #pragma unroll
            for (int q = 0; q < 8; ++q) { xh[q] = z8; xl[q] = z8; }
        }
    }
    __syncthreads();

    // ---- phase B: barrier-free MFMA stream ----
    // step order: X-part first (t=0..7, regs just loaded, freed early),
    // then agg part from LDS (t=8..39).
    const int c0 = wv << 5;

    f16v acc;
    #pragma unroll
    for (int i = 0; i < 16; ++i) acc[i] = 0.f;

    s8v Bb[2][4];
    auto khg_of = [&](int t) {
        return (t < 8) ? (64 + 2 * t + kh8) : (2 * (t - 8) + kh8);
    };
    auto loadB4 = [&](int g, int buf) {
        #pragma unroll
        for (int q = 0; q < 4; ++q) {
            int khg = khg_of(g * 4 + q);
            size_t off = ((size_t)khg * 128 + c0 + m) * 8;
            Bb[buf][q] = *(const s8v*)&Bph[off];
        }
    };
    loadB4(0, 0);

    #pragma unroll
    for (int g = 0; g < 10; ++g) {
        int buf = g & 1;
        if (g < 9) loadB4(g + 1, buf ^ 1);
        #pragma unroll
        for (int q = 0; q < 4; ++q) {
            int t = g * 4 + q;
            if (t < 8) {
                acc = __builtin_amdgcn_mfma_f32_32x32x16_bf16(xl[t], Bb[buf][q], acc, 0, 0, 0);
                acc = __builtin_amdgcn_mfma_f32_32x32x16_bf16(xh[t], Bb[buf][q], acc, 0, 0, 0);
            } else {
                int khg  = 2 * (t - 8) + kh8;
                int slot = m ^ (khg & 31);
                s8v aH = *(const s8v*)&Whi[(khg * 32 + slot) * 8];
                acc = __builtin_amdgcn_mfma_f32_32x32x16_bf16(aH, Bb[buf][q], acc, 0, 0, 0);
            }
        }
    }

    // epilogue: 32x32 C/D: col = lane&31, row = (reg&3) + 8*(reg>>2) + 4*(lane>>5)
    int gc = c0 + m;
    float bv = bias[gc];
    const int rbase = kh8 << 2;
    #pragma unroll
    for (int reg = 0; reg < 16; ++reg) {
        int gr = node0 + rbase + (reg & 3) + ((reg >> 2) << 3);
        if (gr < N) {
            float v = fmaxf(acc[reg] + bv, 0.f);
            unsigned short h = f2bf(v);
            Xoh[(size_t)gr * 128 + gc] = h;
            Xol[(size_t)gr * 128 + gc] = f2bf(v - bf2f(h));
        }
    }
}

// ---------------- gated output ----------------
__global__ __launch_bounds__(256) void output_kernel(
    const int* __restrict__ samples,
    const float* __restrict__ gate_e,
    const float* __restrict__ gate_r,
    const float* __restrict__ ent_emb,
    const float* __restrict__ rel_emb,
    const unsigned short* __restrict__ ctx2h,
    const unsigned short* __restrict__ ctx2l,
    const float* __restrict__ relctx,
    float* __restrict__ out, int S)
{
    int s = blockIdx.x * 2 + (threadIdx.x >> 7);
    if (s >= S) return;
    int p = blockIdx.y;
    int o = threadIdx.x & 127;
    float v;
    if (p == 1) {
        int idx = samples[s * 3 + 1];
        float g = 1.0f / (1.0f + __expf(-gate_r[o]));
        v = g * rel_emb[idx * 128 + o] + (1.0f - g) * relctx[idx * 128 + o];
    } else {
        int idx = samples[s * 3 + (p == 0 ? 0 : 2)];
        float g = 1.0f / (1.0f + __expf(-gate_e[o]));
        float c = bf2f(ctx2h[(size_t)idx * 128 + o]) + bf2f(ctx2l[(size_t)idx * 128 + o]);
        v = g * ent_emb[(size_t)idx * 128 + o] + (1.0f - g) * c;
    }
    out[(size_t)p * S * 128 + (size_t)s * 128 + o] = v;
}

extern "C" void kernel_launch(void* const* d_in, const int* in_sizes, int n_in,
                              void* d_out, int out_size, void* d_ws, size_t ws_size,
                              hipStream_t stream)
{
    const int*   entity     = (const int*)d_in[0];
    const int*   edge_index = (const int*)d_in[1];
    const int*   edge_type  = (const int*)d_in[2];
    const float* edge_norm  = (const float*)d_in[3];
    const int*   samples    = (const int*)d_in[4];
    const float* DAD        = (const float*)d_in[5];
    const float* ent_emb    = (const float*)d_in[6];
    const float* rel_emb    = (const float*)d_in[7];
    const float* ent_tab    = (const float*)d_in[8];
    const float* rel_tab    = (const float*)d_in[9];
    const float* Wrel       = (const float*)d_in[10];
    const float* gate_e     = (const float*)d_in[11];
    const float* gate_r     = (const float*)d_in[12];
    const float* basis1     = (const float*)d_in[13];
    const float* att1       = (const float*)d_in[14];
    const float* root1      = (const float*)d_in[15];
    const float* bias1      = (const float*)d_in[16];
    const float* basis2     = (const float*)d_in[17];
    const float* att2       = (const float*)d_in[18];
    const float* root2      = (const float*)d_in[19];
    const float* bias2      = (const float*)d_in[20];

    const int N  = in_sizes[0];        // 50000
    const int E  = in_sizes[2];        // 200000
    const int S  = in_sizes[4] / 3;    // 20000
    const int NR = in_sizes[9] / 128;  // 200

    unsigned short* X0h = (unsigned short*)d_ws;       // [N,128] bf16
    unsigned short* X0l = X0h + (size_t)N * 128;
    unsigned short* X1h = X0l + (size_t)N * 128;
    unsigned short* X1l = X1h + (size_t)N * 128;
    float4* an1    = (float4*)(X1l + (size_t)N * 128); // [E+4]
    float4* an2    = an1 + (E + 4);                    // [E+4]
    float* Rc      = (float*)(an2 + (E + 4));          // [NR,128]
    int*   deg     = (int*)(Rc + (size_t)NR * 128);    // [N]
    int*   rstart  = deg + N;                          // [N+1]
    int*   cursor  = rstart + N + 1;                   // [N]
    int*   src_s   = cursor + N;                       // [E+4]
    int*   btot    = src_s + E + 4;                    // [64]
    int*   boff    = btot + 64;                        // [64] (unused, keeps layout)
    uintptr_t bt   = ((uintptr_t)(boff + 64) + 15) & ~(uintptr_t)15;
    unsigned short* Bp1h = (unsigned short*)bt;        // [80*128*8]
    unsigned short* Bp2h = Bp1h + 80 * 128 * 8;

    const int egrid = (E + 255) / 256;
    const int lgrid = (N + 31) / 32;
    const int nB    = (N + 1023) / 1024;
    const int x0blocks = (N * 16 + 255) / 256;
    const int b1 = NR;
    const int b2 = NR + 640;
    const int pgrid = b2 + egrid;

    hipMemsetAsync(deg, 0, (size_t)N * sizeof(int), stream);
    prep_kernel<<<pgrid, 256, 0, stream>>>(
        basis1, root1, basis2, root2, Bp1h, Bp2h,
        edge_index, deg, E,
        DAD, rel_tab, Wrel, Rc, NR, b1, b2);
    scanA_kernel<<<nB, 1024, 0, stream>>>(deg, rstart, btot, N);
    scanC_kernel<<<nB, 1024, 0, stream>>>(rstart, cursor, btot, nB, N);
    fill_kernel<<<egrid + x0blocks, 256, 0, stream>>>(
        edge_index, edge_type, edge_norm, cursor, att1, att2, src_s, an1, an2, E,
        ent_tab, entity, X0h, X0l, N, egrid);

    // ---- layer 1: X1 = relu([agg(X0)|X0] @ W1) ----
    layer_kernel<<<lgrid, 256, 0, stream>>>(X0h, X0l, rstart, src_s, an1,
                                            Bp1h, bias1, X1h, X1l, N);
    // ---- layer 2: X0 = relu([agg(X1)|X1] @ W2) ----
    layer_kernel<<<lgrid, 256, 0, stream>>>(X1h, X1l, rstart, src_s, an2,
                                            Bp2h, bias2, X0h, X0l, N);

    // ---- gated output ----
    output_kernel<<<dim3((S + 1) / 2, 3), 256, 0, stream>>>(
        samples, gate_e, gate_r, ent_emb, rel_emb, X0h, X0l, Rc, (float*)d_out, S);
}

// Round 5
// 295.081 us; speedup vs baseline: 1.0421x; 1.0421x over previous
//
#include <hip/hip_runtime.h>
#include <hip/hip_bf16.h>

typedef short s8v  __attribute__((ext_vector_type(8)));
typedef float f16v __attribute__((ext_vector_type(16)));

__device__ __forceinline__ unsigned short f2bf(float x) {   // RTN-even
    unsigned u = __float_as_uint(x);
    unsigned r = ((u >> 16) & 1u) + 0x7FFFu;
    return (unsigned short)((u + r) >> 16);
}
__device__ __forceinline__ float bf2f(unsigned short h) {
    return __uint_as_float(((unsigned)h) << 16);
}

// ---------------- hist only (critical chain head, keep it tiny) ----------------
__global__ __launch_bounds__(256) void hist_kernel(
    const int* __restrict__ edge_index, int* __restrict__ deg, int E)
{
    int e = blockIdx.x * 256 + threadIdx.x;
    if (e < E) atomicAdd(&deg[edge_index[E + e]], 1);
}

// ---------------- CSR scan ----------------
__global__ __launch_bounds__(1024) void scanA_kernel(
    const int* __restrict__ deg, int* __restrict__ row_start,
    int* __restrict__ btot, int N)
{
    __shared__ int wtot[16];
    __shared__ int woff[16];
    const int tid = threadIdx.x, lane = tid & 63, wid = tid >> 6;
    int i = blockIdx.x * 1024 + tid;
    int v = (i < N) ? deg[i] : 0;
    int x = v;
    #pragma unroll
    for (int d = 1; d < 64; d <<= 1) {
        int t = __shfl_up(x, d, 64);
        if (lane >= d) x += t;
    }
    if (lane == 63) wtot[wid] = x;
    __syncthreads();
    if (wid == 0 && lane < 16) {
        int s = wtot[lane];
        int y = s;
        #pragma unroll
        for (int d = 1; d < 16; d <<= 1) {
            int t = __shfl_up(y, d, 16);
            if (lane >= d) y += t;
        }
        woff[lane] = y - s;
        if (lane == 15) btot[blockIdx.x] = y;
    }
    __syncthreads();
    if (i < N) row_start[i] = woff[wid] + (x - v);
}

// scanC with scanB inlined: every block redundantly wave-scans the <=64
// block totals (cheap), then applies its own exclusive offset.
__global__ __launch_bounds__(1024) void scanC_kernel(
    int* __restrict__ row_start, int* __restrict__ cursor,
    const int* __restrict__ btot, int nB, int N)
{
    __shared__ int incl[64];
    const int tid = threadIdx.x;
    if (tid < 64) {
        int v = (tid < nB) ? btot[tid] : 0;
        int x = v;
        #pragma unroll
        for (int d = 1; d < 64; d <<= 1) {
            int t = __shfl_up(x, d, 64);
            if (tid >= d) x += t;
        }
        incl[tid] = x;
    }
    __syncthreads();
    int off = (blockIdx.x == 0) ? 0 : incl[blockIdx.x - 1];
    int i = blockIdx.x * 1024 + tid;
    if (i < N) {
        int r = row_start[i] + off;
        row_start[i] = r;
        cursor[i]    = r;
    }
    if (blockIdx.x == (unsigned)(nB - 1) && tid == 0)
        row_start[N] = incl[nB - 1];
}

// ---------------- mega: relctx | fill | x0 | bprep (all post-scan, one dispatch) ----------------
__global__ __launch_bounds__(256) void mega_kernel(
    // relctx
    const float* __restrict__ DAD, const float* __restrict__ rtab,
    const float* __restrict__ Wrel, float* __restrict__ Rc, int NR,
    // fill
    const int* __restrict__ edge_index, const int* __restrict__ edge_type,
    const float* __restrict__ edge_norm, int* __restrict__ cursor,
    const float* __restrict__ att1, const float* __restrict__ att2,
    int* __restrict__ src_s, float4* __restrict__ an1, float4* __restrict__ an2, int E,
    // x0
    const float* __restrict__ tab, const int* __restrict__ entity,
    unsigned short* __restrict__ X0h, unsigned short* __restrict__ X0l, int N,
    // bprep
    const float* __restrict__ basis1, const float* __restrict__ root1,
    const float* __restrict__ basis2, const float* __restrict__ root2,
    unsigned short* __restrict__ Bp1h, unsigned short* __restrict__ Bp2h,
    int c1, int c2, int c3)     // c1=NR, c2=c1+egrid, c3=c2+x0blocks
{
    __shared__ float smem[384];
    const int b = blockIdx.x, tid = threadIdx.x;

    if (b < c1) {                        // ---- relctx ----
        float* part = smem;              // [2][128]
        float* r1s  = smem + 256;        // [128]
        int r = b;
        int o = tid & 127, q = tid >> 7;
        float s = 0.f;
        for (int j = q; j < NR; j += 2)
            s = fmaf(DAD[r * NR + j], rtab[j * 128 + o], s);
        part[q * 128 + o] = s;
        __syncthreads();
        if (tid < 128) r1s[tid] = part[tid] + part[128 + tid];
        __syncthreads();
        float s2 = 0.f;
        #pragma unroll 8
        for (int k = q * 64; k < q * 64 + 64; ++k)
            s2 = fmaf(r1s[k], Wrel[k * 128 + o], s2);
        part[q * 128 + o] = s2;
        __syncthreads();
        if (tid < 128)
            Rc[r * 128 + tid] = fmaxf(part[tid] + part[128 + tid], 0.f);
    } else if (b < c2) {                 // ---- fill ----
        int e = (b - c1) * 256 + tid;
        if (e >= E) return;
        int dst = edge_index[E + e];
        int et  = edge_type[e];
        float n = edge_norm[e];
        int pos = atomicAdd(&cursor[dst], 1);
        src_s[pos] = edge_index[e];
        float4 a1 = *(const float4*)&att1[(size_t)et * 4];
        float4 a2 = *(const float4*)&att2[(size_t)et * 4];
        an1[pos] = make_float4(n * a1.x, n * a1.y, n * a1.z, n * a1.w);
        an2[pos] = make_float4(n * a2.x, n * a2.y, n * a2.z, n * a2.w);
    } else if (b < c3) {                 // ---- X0 = tab[entity] hi/lo ----
        int idx = (b - c2) * 256 + tid;  // 8 dims / thread (2 indep float4)
        int nn = idx >> 4, part = idx & 15;
        if (nn < N) {
            int src = entity[nn];
            const float4* sp = (const float4*)&tab[(size_t)src * 128 + part * 8];
            float4 v0 = sp[0], v1 = sp[1];
            float vs[8] = {v0.x, v0.y, v0.z, v0.w, v1.x, v1.y, v1.z, v1.w};
            s8v h8, l8;
            #pragma unroll
            for (int j = 0; j < 8; ++j) {
                unsigned short h = f2bf(vs[j]);
                h8[j] = (short)h;
                l8[j] = (short)f2bf(vs[j] - bf2f(h));
            }
            *(s8v*)&X0h[(size_t)nn * 128 + part * 8] = h8;
            *(s8v*)&X0l[(size_t)nn * 128 + part * 8] = l8;
        }
    } else {                             // ---- B prep (hi only) ----
        int bb = b - c3;
        int layer = bb >= 320;
        int idx = (layer ? bb - 320 : bb) * 256 + tid;
        int n = idx & 127, k = idx >> 7;
        const float* basis = layer ? basis2 : basis1;
        const float* root  = layer ? root2  : root1;
        float v = (k < 512) ? basis[((k & 3) << 14) + ((k >> 2) << 7) + n]
                            : root[((k - 512) << 7) + n];
        size_t pos = (((size_t)(k >> 3) * 128) + n) * 8 + (k & 7);
        (layer ? Bp2h : Bp1h)[pos] = f2bf(v);
    }
}

// ---------------- FUSED layer: Xout = relu([agg(X)|X] @ B + bias) ----------------
// 512 threads, 32 nodes. Gather: 32 groups x 16 lanes, ONE node per group
// (no max-degree padding across nodes; s8v 16B row loads halve VMEM instrs).
// Waves 4-7 exit after the single barrier; waves 0-3 run the barrier-free
// MFMA stream (B double-buffered global->reg, own-row X direct from global).
__global__ __launch_bounds__(512, 4) void layer_kernel(
    const unsigned short* __restrict__ Xh,    // [N,128] bf16 hi
    const unsigned short* __restrict__ Xl,    // [N,128] bf16 lo
    const int* __restrict__ row_start,
    const int* __restrict__ src_s,
    const float4* __restrict__ an,
    const unsigned short* __restrict__ Bph,   // packed [80][128][8] bf16
    const float* __restrict__ bias,
    unsigned short* __restrict__ Xoh,
    unsigned short* __restrict__ Xol,
    int N)
{
    __shared__ unsigned short Whi[64 * 32 * 8];   // 32 KB (agg part only)

    const int tid   = threadIdx.x;
    const int node0 = blockIdx.x * 32;

    // ---- phase A: gather, 1 node per 16-lane group ----
    {
        const int g = tid >> 4, l = tid & 15;     // lane l covers dims 8l..8l+7
        const int gn = node0 + g;
        const bool ok = gn < N;
        int s0 = ok ? row_start[gn] : 0;
        int s1 = ok ? row_start[gn + 1] : 0;
        float acc[8][4];                          // [local dim][basis]
        #pragma unroll
        for (int d = 0; d < 8; ++d)
            #pragma unroll
            for (int c = 0; c < 4; ++c) acc[d][c] = 0.f;

        const int se = s1 - 1;
        for (int q0 = s0; q0 < s1; q0 += 4) {
            int q1 = min(q0 + 1, se);
            int q2 = min(q0 + 2, se);
            int q3 = min(q0 + 3, se);
            int sA = src_s[q0], sB = src_s[q1];
            int sC = src_s[q2], sD = src_s[q3];
            float4 aA = an[q0], aB = an[q1];
            float4 aC = an[q2], aD = an[q3];
            if (q0 + 1 > se) aB = make_float4(0.f, 0.f, 0.f, 0.f);
            if (q0 + 2 > se) aC = make_float4(0.f, 0.f, 0.f, 0.f);
            if (q0 + 3 > se) aD = make_float4(0.f, 0.f, 0.f, 0.f);
            s8v hA = *(const s8v*)&Xh[(size_t)sA * 128 + (l << 3)];
            s8v hB = *(const s8v*)&Xh[(size_t)sB * 128 + (l << 3)];
            s8v hC = *(const s8v*)&Xh[(size_t)sC * 128 + (l << 3)];
            s8v hD = *(const s8v*)&Xh[(size_t)sD * 128 + (l << 3)];
            #pragma unroll
            for (int d = 0; d < 8; ++d) {
                float xA = bf2f((unsigned short)hA[d]);
                float xB = bf2f((unsigned short)hB[d]);
                float xC = bf2f((unsigned short)hC[d]);
                float xD = bf2f((unsigned short)hD[d]);
                acc[d][0] = fmaf(aA.x, xA, fmaf(aB.x, xB, fmaf(aC.x, xC, fmaf(aD.x, xD, acc[d][0]))));
                acc[d][1] = fmaf(aA.y, xA, fmaf(aB.y, xB, fmaf(aC.y, xC, fmaf(aD.y, xD, acc[d][1]))));
                acc[d][2] = fmaf(aA.z, xA, fmaf(aB.z, xB, fmaf(aC.z, xC, fmaf(aD.z, xD, acc[d][2]))));
                acc[d][3] = fmaf(aA.w, xA, fmaf(aB.w, xB, fmaf(aC.w, xC, fmaf(aD.w, xD, acc[d][3]))));
            }
        }
        float inv = 1.0f / fmaxf((float)(s1 - s0), 1.0f);
        #pragma unroll
        for (int f = 0; f < 4; ++f) {             // fragment kh = 4l+f
            int kh   = 4 * l + f;
            int slot = g ^ (kh & 31);
            s8v h8;
            #pragma unroll
            for (int j = 0; j < 4; ++j) {
                h8[j]     = (short)f2bf(acc[2 * f][j]     * inv);
                h8[4 + j] = (short)f2bf(acc[2 * f + 1][j] * inv);
            }
            *(s8v*)&Whi[(kh * 32 + slot) * 8] = h8;
        }
    }

    // ---- own-row X fragments direct from global (waves 0-3 only) ----
    const int lane = tid & 63, wv = tid >> 6;
    const int m    = lane & 31;
    const int kh8  = lane >> 5;
    s8v xh[8], xl[8];
    if (tid < 256) {
        const s8v z8 = {0, 0, 0, 0, 0, 0, 0, 0};
        int gn  = node0 + m;
        bool ok = gn < N;
        size_t xbase = (size_t)(ok ? gn : 0) * 128;
        #pragma unroll
        for (int q = 0; q < 8; ++q) {
            int dk = 2 * q + kh8;                 // == khg - 64
            xh[q] = *(const s8v*)&Xh[xbase + dk * 8];
            xl[q] = *(const s8v*)&Xl[xbase + dk * 8];
        }
        if (!ok) {
            #pragma unroll
            for (int q = 0; q < 8; ++q) { xh[q] = z8; xl[q] = z8; }
        }
    }
    __syncthreads();
    if (tid >= 256) return;                       // waves 4-7 done (no more barriers)

    // ---- phase B: barrier-free MFMA stream ----
    // X-part first (t=0..7, regs just loaded, freed early), then agg from LDS.
    const int c0 = wv << 5;

    f16v acc;
    #pragma unroll
    for (int i = 0; i < 16; ++i) acc[i] = 0.f;

    s8v Bb[2][4];
    auto khg_of = [&](int t) {
        return (t < 8) ? (64 + 2 * t + kh8) : (2 * (t - 8) + kh8);
    };
    auto loadB4 = [&](int g, int buf) {
        #pragma unroll
        for (int q = 0; q < 4; ++q) {
            int khg = khg_of(g * 4 + q);
            size_t off = ((size_t)khg * 128 + c0 + m) * 8;
            Bb[buf][q] = *(const s8v*)&Bph[off];
        }
    };
    loadB4(0, 0);

    #pragma unroll
    for (int g = 0; g < 10; ++g) {
        int buf = g & 1;
        if (g < 9) loadB4(g + 1, buf ^ 1);
        #pragma unroll
        for (int q = 0; q < 4; ++q) {
            int t = g * 4 + q;
            if (t < 8) {
                acc = __builtin_amdgcn_mfma_f32_32x32x16_bf16(xl[t], Bb[buf][q], acc, 0, 0, 0);
                acc = __builtin_amdgcn_mfma_f32_32x32x16_bf16(xh[t], Bb[buf][q], acc, 0, 0, 0);
            } else {
                int khg  = 2 * (t - 8) + kh8;
                int slot = m ^ (khg & 31);
                s8v aH = *(const s8v*)&Whi[(khg * 32 + slot) * 8];
                acc = __builtin_amdgcn_mfma_f32_32x32x16_bf16(aH, Bb[buf][q], acc, 0, 0, 0);
            }
        }
    }

    // epilogue: 32x32 C/D: col = lane&31, row = (reg&3) + 8*(reg>>2) + 4*(lane>>5)
    int gc = c0 + m;
    float bv = bias[gc];
    const int rbase = kh8 << 2;
    #pragma unroll
    for (int reg = 0; reg < 16; ++reg) {
        int gr = node0 + rbase + (reg & 3) + ((reg >> 2) << 3);
        if (gr < N) {
            float v = fmaxf(acc[reg] + bv, 0.f);
            unsigned short h = f2bf(v);
            Xoh[(size_t)gr * 128 + gc] = h;
            Xol[(size_t)gr * 128 + gc] = f2bf(v - bf2f(h));
        }
    }
}

// ---------------- gated output: 8 samples per block ----------------
__global__ __launch_bounds__(256) void output_kernel(
    const int* __restrict__ samples,
    const float* __restrict__ gate_e,
    const float* __restrict__ gate_r,
    const float* __restrict__ ent_emb,
    const float* __restrict__ rel_emb,
    const unsigned short* __restrict__ ctx2h,
    const unsigned short* __restrict__ ctx2l,
    const float* __restrict__ relctx,
    float* __restrict__ out, int S)
{
    const int p   = blockIdx.y;
    const int o   = threadIdx.x & 127;
    const int sub = threadIdx.x >> 7;
    const float g = (p == 1) ? 1.0f / (1.0f + __expf(-gate_r[o]))
                             : 1.0f / (1.0f + __expf(-gate_e[o]));
    const int s0 = blockIdx.x * 8 + sub;
    #pragma unroll
    for (int k = 0; k < 4; ++k) {
        int s = s0 + k * 2;
        if (s >= S) break;
        float v;
        if (p == 1) {
            int idx = samples[s * 3 + 1];
            v = g * rel_emb[idx * 128 + o] + (1.0f - g) * relctx[idx * 128 + o];
        } else {
            int idx = samples[s * 3 + (p == 0 ? 0 : 2)];
            float c = bf2f(ctx2h[(size_t)idx * 128 + o]) + bf2f(ctx2l[(size_t)idx * 128 + o]);
            v = g * ent_emb[(size_t)idx * 128 + o] + (1.0f - g) * c;
        }
        out[(size_t)p * S * 128 + (size_t)s * 128 + o] = v;
    }
}

extern "C" void kernel_launch(void* const* d_in, const int* in_sizes, int n_in,
                              void* d_out, int out_size, void* d_ws, size_t ws_size,
                              hipStream_t stream)
{
    const int*   entity     = (const int*)d_in[0];
    const int*   edge_index = (const int*)d_in[1];
    const int*   edge_type  = (const int*)d_in[2];
    const float* edge_norm  = (const float*)d_in[3];
    const int*   samples    = (const int*)d_in[4];
    const float* DAD        = (const float*)d_in[5];
    const float* ent_emb    = (const float*)d_in[6];
    const float* rel_emb    = (const float*)d_in[7];
    const float* ent_tab    = (const float*)d_in[8];
    const float* rel_tab    = (const float*)d_in[9];
    const float* Wrel       = (const float*)d_in[10];
    const float* gate_e     = (const float*)d_in[11];
    const float* gate_r     = (const float*)d_in[12];
    const float* basis1     = (const float*)d_in[13];
    const float* att1       = (const float*)d_in[14];
    const float* root1      = (const float*)d_in[15];
    const float* bias1      = (const float*)d_in[16];
    const float* basis2     = (const float*)d_in[17];
    const float* att2       = (const float*)d_in[18];
    const float* root2      = (const float*)d_in[19];
    const float* bias2      = (const float*)d_in[20];

    const int N  = in_sizes[0];        // 50000
    const int E  = in_sizes[2];        // 200000
    const int S  = in_sizes[4] / 3;    // 20000
    const int NR = in_sizes[9] / 128;  // 200

    unsigned short* X0h = (unsigned short*)d_ws;       // [N,128] bf16
    unsigned short* X0l = X0h + (size_t)N * 128;
    unsigned short* X1h = X0l + (size_t)N * 128;
    unsigned short* X1l = X1h + (size_t)N * 128;
    float4* an1    = (float4*)(X1l + (size_t)N * 128); // [E+4]
    float4* an2    = an1 + (E + 4);                    // [E+4]
    float* Rc      = (float*)(an2 + (E + 4));          // [NR,128]
    int*   deg     = (int*)(Rc + (size_t)NR * 128);    // [N]
    int*   rstart  = deg + N;                          // [N+1]
    int*   cursor  = rstart + N + 1;                   // [N]
    int*   src_s   = cursor + N;                       // [E+4]
    int*   btot    = src_s + E + 4;                    // [64]
    int*   boff    = btot + 64;                        // [64] (keeps layout)
    uintptr_t bt   = ((uintptr_t)(boff + 64) + 15) & ~(uintptr_t)15;
    unsigned short* Bp1h = (unsigned short*)bt;        // [80*128*8]
    unsigned short* Bp2h = Bp1h + 80 * 128 * 8;

    const int egrid = (E + 255) / 256;
    const int lgrid = (N + 31) / 32;
    const int nB    = (N + 1023) / 1024;
    const int x0blocks = (N * 16 + 255) / 256;
    const int c1 = NR;
    const int c2 = c1 + egrid;
    const int c3 = c2 + x0blocks;
    const int mgrid = c3 + 640;

    hipMemsetAsync(deg, 0, (size_t)N * sizeof(int), stream);
    hist_kernel<<<egrid, 256, 0, stream>>>(edge_index, deg, E);
    scanA_kernel<<<nB, 1024, 0, stream>>>(deg, rstart, btot, N);
    scanC_kernel<<<nB, 1024, 0, stream>>>(rstart, cursor, btot, nB, N);
    mega_kernel<<<mgrid, 256, 0, stream>>>(
        DAD, rel_tab, Wrel, Rc, NR,
        edge_index, edge_type, edge_norm, cursor, att1, att2, src_s, an1, an2, E,
        ent_tab, entity, X0h, X0l, N,
        basis1, root1, basis2, root2, Bp1h, Bp2h,
        c1, c2, c3);

    // ---- layer 1: X1 = relu([agg(X0)|X0] @ W1) ----
    layer_kernel<<<lgrid, 512, 0, stream>>>(X0h, X0l, rstart, src_s, an1,
                                            Bp1h, bias1, X1h, X1l, N);
    // ---- layer 2: X0 = relu([agg(X1)|X1] @ W2) ----
    layer_kernel<<<lgrid, 512, 0, stream>>>(X1h, X1l, rstart, src_s, an2,
                                            Bp2h, bias2, X0h, X0l, N);

    // ---- gated output ----
    output_kernel<<<dim3((S + 7) / 8, 3), 256, 0, stream>>>(
        samples, gate_e, gate_r, ent_emb, rel_emb, X0h, X0l, Rc, (float*)d_out, S);
}